// Round 5
// baseline (276.106 us; speedup 1.0000x reference)
//
#include <hip/hip_runtime.h>
#include <hip/hip_bf16.h>
#include <stdint.h>

#define EMBED 1024
#define HEADS 16
#define CTX   2048
#define BATCH 4
#define HD    64
#define M_TOT (BATCH*CTX)   // 8192

typedef unsigned short u16;
typedef __attribute__((ext_vector_type(8))) short short8;   // 8 bf16 (4 VGPRs)
typedef __attribute__((ext_vector_type(4))) float floatx4;  // MFMA C/D

typedef const __attribute__((address_space(1))) unsigned int g_u32;
typedef __attribute__((address_space(3))) unsigned int l_u32;

__device__ __forceinline__ void async16(const void* g, void* l) {
    __builtin_amdgcn_global_load_lds((g_u32*)g, (l_u32*)l, 16, 0, 0);
}

__device__ __forceinline__ u16 f2bf(float f) {          // round-nearest-even
    uint32_t u = __float_as_uint(f);
    uint32_t r = (u + 0x7FFFu + ((u >> 16) & 1u)) >> 16;
    return (u16)r;
}

// ---------------- fused fp32 -> bf16 convert (x + 4 weight matrices, 1 launch) ----------------
__global__ void cvt_all(const float* __restrict__ x,
                        const float* __restrict__ Wq, const float* __restrict__ Wk,
                        const float* __restrict__ Wv, const float* __restrict__ Wp,
                        u16* __restrict__ xb,
                        u16* __restrict__ wqb, u16* __restrict__ wkb,
                        u16* __restrict__ wvb, u16* __restrict__ wpb) {
    const int b = blockIdx.x;
    const float* src; u16* dst; int base;
    if (b < 8192)       { src = x;  dst = xb;  base = b; }
    else if (b < 9216)  { src = Wq; dst = wqb; base = b - 8192; }
    else if (b < 10240) { src = Wk; dst = wkb; base = b - 9216; }
    else if (b < 11264) { src = Wv; dst = wvb; base = b - 10240; }
    else                { src = Wp; dst = wpb; base = b - 11264; }
    const int i = (base * 256 + threadIdx.x) * 4;
    float4 f = *(const float4*)(src + i);
    ushort4 o;
    o.x = f2bf(f.x); o.y = f2bf(f.y); o.z = f2bf(f.z); o.w = f2bf(f.w);
    *(ushort4*)(dst + i) = o;
}

// ================= fused QKV GEMM, 128x128 tile, BK=64 (R0-verified structure) =================
__global__ __launch_bounds__(256)
void gemm_qkv(const u16* __restrict__ A,
              const u16* __restrict__ Wq, const u16* __restrict__ Wk, const u16* __restrict__ Wv,
              const float* __restrict__ bq, const float* __restrict__ bk, const float* __restrict__ bv,
              u16* __restrict__ oq, u16* __restrict__ ok, u16* __restrict__ ov,
              float qscale)
{
    __shared__ u16 As[128*64];   // 16 KB
    __shared__ u16 Bs[128*64];   // 16 KB
    const int tid  = threadIdx.x;
    const int lane = tid & 63;
    const int wid  = tid >> 6;
    const int wm = wid >> 1, wn = wid & 1;
    const int quad = lane >> 4;
    const int l16  = lane & 15;
    const int bm0 = blockIdx.x * 128;
    const int sel = blockIdx.y >> 3;          // 0=Q 1=K 2=V
    const int bn0 = (blockIdx.y & 7) * 128;

    const u16*  Bw   = (sel == 0) ? Wq : (sel == 1) ? Wk : Wv;
    const float* bias = (sel == 0) ? bq : (sel == 1) ? bk : bv;
    u16*        out  = (sel == 0) ? oq : (sel == 1) ? ok : ov;
    const float scale = (sel == 0) ? qscale : 1.0f;

    floatx4 acc[4][4] = {};

    const int r0   = tid >> 3;
    const int joff = ((tid & 7) ^ ((tid >> 3) & 7)) * 8;   // shorts
    const u16* Ag0 = A  + (size_t)(bm0 + r0      ) * EMBED + joff;
    const u16* Ag1 = A  + (size_t)(bm0 + r0 + 32 ) * EMBED + joff;
    const u16* Ag2 = A  + (size_t)(bm0 + r0 + 64 ) * EMBED + joff;
    const u16* Ag3 = A  + (size_t)(bm0 + r0 + 96 ) * EMBED + joff;
    const u16* Bg0 = Bw + (size_t)(bn0 + r0      ) * EMBED + joff;
    const u16* Bg1 = Bw + (size_t)(bn0 + r0 + 32 ) * EMBED + joff;
    const u16* Bg2 = Bw + (size_t)(bn0 + r0 + 64 ) * EMBED + joff;
    const u16* Bg3 = Bw + (size_t)(bn0 + r0 + 96 ) * EMBED + joff;
    char* AsB = (char*)As;
    char* BsB = (char*)Bs;
    const int wbyte = wid * 1024;

    const int fpos0 = (quad ^ (l16 & 7)) * 8;
    const int fpos1 = fpos0 ^ 32;

    for (int kk = 0; kk < EMBED; kk += 64) {
        __syncthreads();
        async16(Ag0 + kk, AsB + wbyte);
        async16(Ag1 + kk, AsB + wbyte + 4096);
        async16(Ag2 + kk, AsB + wbyte + 8192);
        async16(Ag3 + kk, AsB + wbyte + 12288);
        async16(Bg0 + kk, BsB + wbyte);
        async16(Bg1 + kk, BsB + wbyte + 4096);
        async16(Bg2 + kk, BsB + wbyte + 8192);
        async16(Bg3 + kk, BsB + wbyte + 12288);
        __syncthreads();

#pragma unroll
        for (int ks = 0; ks < 2; ks++) {
            const int fp = ks ? fpos1 : fpos0;
            short8 a[4], b[4];
#pragma unroll
            for (int i = 0; i < 4; i++)
                a[i] = *(const short8*)(As + (wm*64 + i*16 + l16)*64 + fp);
#pragma unroll
            for (int i = 0; i < 4; i++)
                b[i] = *(const short8*)(Bs + (wn*64 + i*16 + l16)*64 + fp);
#pragma unroll
            for (int i = 0; i < 4; i++)
#pragma unroll
                for (int j = 0; j < 4; j++)
                    acc[i][j] = __builtin_amdgcn_mfma_f32_16x16x32_bf16(a[i], b[j], acc[i][j], 0, 0, 0);
        }
    }

#pragma unroll
    for (int i = 0; i < 4; i++) {
#pragma unroll
        for (int j = 0; j < 4; j++) {
            const int col = bn0 + wn*64 + j*16 + l16;
            const float bvv = bias[col];
#pragma unroll
            for (int r = 0; r < 4; r++) {
                const int row = bm0 + wm*64 + i*16 + quad*4 + r;
                const float v = (acc[i][j][r] + bvv) * scale;
                const int bb = row >> 11, t = row & 2047;
                const int hh = col >> 6,  d = col & 63;
                if (sel != 2)
                    out[((size_t)(bb*HEADS + hh)*CTX + t)*HD + d] = f2bf(v);
                else
                    out[((size_t)(bb*HEADS + hh)*HD + d)*CTX + t] = f2bf(v);
            }
        }
    }
}

// ================= projection GEMM (fp32 out), 128x64 tile, BK=64, ping-pong dbuf =================
// Re-tiled for occupancy: grid 64x16 = 1024 blocks (was 512 -> 2/CU); LDS 48 KB
// -> 3 blocks/CU co-resident. 4 waves = 2M x 2N, wave tile 64x32, acc[4][2].
// Staging pattern identical to the verified ping-pong (one barrier/iter).
__global__ __launch_bounds__(256)
void gemm_proj(const u16* __restrict__ A, const u16* __restrict__ Bw,
               const float* __restrict__ bias, float* __restrict__ out)
{
    __shared__ u16 As[2][128*64];   // 2 x 16 KB
    __shared__ u16 Bs[2][64*64];    // 2 x 8 KB
    const int tid  = threadIdx.x;
    const int lane = tid & 63;
    const int wid  = tid >> 6;
    const int wm = wid >> 1, wn = wid & 1;
    const int quad = lane >> 4;
    const int l16  = lane & 15;
    const int bm0 = blockIdx.x * 128;
    const int bn0 = blockIdx.y * 64;

    floatx4 acc[4][2] = {};

    const int r0   = tid >> 3;
    const int joff = ((tid & 7) ^ ((tid >> 3) & 7)) * 8;
    const u16* Ag0 = A  + (size_t)(bm0 + r0      ) * EMBED + joff;
    const u16* Ag1 = A  + (size_t)(bm0 + r0 + 32 ) * EMBED + joff;
    const u16* Ag2 = A  + (size_t)(bm0 + r0 + 64 ) * EMBED + joff;
    const u16* Ag3 = A  + (size_t)(bm0 + r0 + 96 ) * EMBED + joff;
    const u16* Bg0 = Bw + (size_t)(bn0 + r0      ) * EMBED + joff;
    const u16* Bg1 = Bw + (size_t)(bn0 + r0 + 32 ) * EMBED + joff;
    const int wbyte = wid * 1024;
    const int fpos0 = (quad ^ (l16 & 7)) * 8;
    const int fpos1 = fpos0 ^ 32;

    auto stage = [&](int it, int buf) {
        char* AsB = (char*)As + buf * 16384;
        char* BsB = (char*)Bs + buf * 8192;
        const int kk = it * 64;
        async16(Ag0 + kk, AsB + wbyte);
        async16(Ag1 + kk, AsB + wbyte + 4096);
        async16(Ag2 + kk, AsB + wbyte + 8192);
        async16(Ag3 + kk, AsB + wbyte + 12288);
        async16(Bg0 + kk, BsB + wbyte);
        async16(Bg1 + kk, BsB + wbyte + 4096);
    };

    int buf = 0;
    stage(0, 0);

#pragma unroll 1
    for (int it = 0; it < EMBED/64; ++it) {
        __syncthreads();                    // drains stage(it) (issued last iter)
        if (it + 1 < EMBED/64) stage(it + 1, buf ^ 1);

        const u16* Ac = &As[buf][0];
        const u16* Bc = &Bs[buf][0];
#pragma unroll
        for (int ks = 0; ks < 2; ks++) {
            const int fp = ks ? fpos1 : fpos0;
            short8 a[4], b[2];
#pragma unroll
            for (int i = 0; i < 4; i++)
                a[i] = *(const short8*)(Ac + (wm*64 + i*16 + l16)*64 + fp);
#pragma unroll
            for (int j = 0; j < 2; j++)
                b[j] = *(const short8*)(Bc + (wn*32 + j*16 + l16)*64 + fp);
#pragma unroll
            for (int i = 0; i < 4; i++)
#pragma unroll
                for (int j = 0; j < 2; j++)
                    acc[i][j] = __builtin_amdgcn_mfma_f32_16x16x32_bf16(a[i], b[j], acc[i][j], 0, 0, 0);
        }
        buf ^= 1;
    }

#pragma unroll
    for (int i = 0; i < 4; i++) {
#pragma unroll
        for (int j = 0; j < 2; j++) {
            const int col = bn0 + wn*32 + j*16 + l16;
            const float bvv = bias[col];
#pragma unroll
            for (int r = 0; r < 4; r++) {
                const int row = bm0 + wm*64 + i*16 + quad*4 + r;
                out[(size_t)row * EMBED + col] = acc[i][j][r] + bvv;
            }
        }
    }
}

// ---------------- flash attention: 128 q/block, S^T order, swizzled P, MFMA row-sum ----------------
// R0-verified 128q structure. lsum via ones-MFMA: lacc[st] = mfma(pf, ONES, lacc)
// gives row-sums replicated across cols in the C-layout (reg r <-> q=quad*4+r) --
// exactly the indexing the O-write uses, so the end-of-pass shuffles vanish.
__global__ __launch_bounds__(256)
void attn_kernel(const u16* __restrict__ Q, const u16* __restrict__ K,
                 const u16* __restrict__ Vt, u16* __restrict__ O)
{
    __shared__ u16 Ks[2][64*64];     // 2 x 8 KB
    __shared__ u16 Vs[2][64*64];     // 2 x 8 KB   Vs[d][ki]
    __shared__ u16 Ps[4*32*64];      // 16 KB, per-wave 32 rows x 64 ki

    const int tid  = threadIdx.x, lane = tid & 63, w = tid >> 6;
    const int quad = lane >> 4, l16 = lane & 15;

    const int lid  = blockIdx.x;            // 0..511
    const int xcd  = lid & 7;
    const int slot = lid >> 3;              // 0..63
    const int bh   = xcd * 8 + (slot >> 3);
    const int bx   = slot & 7;              // 0..7
    const int h    = bh & (HEADS - 1);
    const int b    = bh >> 4;

    const u16* Qh = Q  + (size_t)bh * CTX * HD;
    const u16* Kh = K  + (size_t)bh * CTX * HD;
    const u16* Vh = Vt + (size_t)bh * HD * CTX;

    const int srow = tid >> 3;
    const int joff = ((tid & 7) ^ (srow & 7)) * 8;
    const int wbyte = w * 1024;
    char* PwB = (char*)(Ps + w * 32 * 64);
    const int sw = l16 & 7;                 // swizzle key (row&7 for all our rows)

    short8 ones;                            // bf16 1.0 x8
#pragma unroll
    for (int i = 0; i < 8; i++) ones[i] = (short)0x3F80;

    auto stage = [&](int kt, int buf) {
        char* kb = (char*)(&Ks[buf][0]) + wbyte;
        char* vb = (char*)(&Vs[buf][0]) + wbyte;
        async16(Kh + (size_t)(kt*64 + srow     )*HD + joff, kb);
        async16(Kh + (size_t)(kt*64 + srow + 32)*HD + joff, kb + 4096);
        async16(Vh + (size_t)(srow     )*CTX + kt*64 + joff, vb);
        async16(Vh + (size_t)(srow + 32)*CTX + kt*64 + joff, vb + 4096);
    };

    int par = 0;
    stage(0, 0);

#pragma unroll 1
    for (int pass = 0; pass < 2; pass++) {
        const int qb  = (pass == 0) ? bx : (15 - bx);
        const int qb0 = qb * 128;
        const int KT  = 2*qb + 2;

        // Q fragments (B-operand: n=q=l16, k=d): qf[subtile][kstep]
        short8 qf[2][2];
#pragma unroll
        for (int st = 0; st < 2; st++)
#pragma unroll
            for (int ks = 0; ks < 2; ks++)
                qf[st][ks] = *(const short8*)(Qh + (size_t)(qb0 + w*32 + st*16 + l16)*HD
                                              + ks*32 + quad*8);

        floatx4 lacc[2] = {};        // row-sum accumulators (ones-MFMA)
        floatx4 o_acc[2][4] = {};

        for (int kt = 0; kt < KT; kt++) {
            __syncthreads();   // drains stage(kt), in flight since previous compute

            if (kt + 1 < KT)      stage(kt + 1, par ^ 1);
            else if (pass == 0)   stage(0,      par ^ 1);

            const char* KcB = (const char*)(&Ks[par][0]);
            const char* VcB = (const char*)(&Vs[par][0]);

            // S^T = K Q^T : m=ki (row=quad*4+r), n=q (col=l16)
            floatx4 s[2][4] = {};
#pragma unroll
            for (int ks = 0; ks < 2; ks++) {
#pragma unroll
                for (int ni = 0; ni < 4; ni++) {
                    short8 kf = *(const short8*)(KcB + (ni*16 + l16)*128
                                                 + (((4*ks + quad) ^ sw) * 16));
                    s[0][ni] = __builtin_amdgcn_mfma_f32_16x16x32_bf16(kf, qf[0][ks], s[0][ni], 0, 0, 0);
                    s[1][ni] = __builtin_amdgcn_mfma_f32_16x16x32_bf16(kf, qf[1][ks], s[1][ni], 0, 0, 0);
                }
            }

            // P = exp2(S'), mask on last two tiles, packed b64 stores to swizzled P
            const bool mt = (kt >= 2*qb);
            const int key0 = kt * 64;
#pragma unroll
            for (int st = 0; st < 2; st++) {
                const int qrow = qb0 + w*32 + st*16 + l16;
#pragma unroll
                for (int ni = 0; ni < 4; ni++) {
                    float p[4];
#pragma unroll
                    for (int r = 0; r < 4; r++) {
                        float v = s[st][ni][r];
                        if (mt) {
                            const int key = key0 + ni*16 + quad*4 + r;
                            if (key > qrow) v = -INFINITY;
                        }
                        p[r] = __builtin_amdgcn_exp2f(v);
                    }
                    uint2 pk;
                    pk.x = (__float_as_uint(p[0]) >> 16) | (__float_as_uint(p[1]) & 0xFFFF0000u);
                    pk.y = (__float_as_uint(p[2]) >> 16) | (__float_as_uint(p[3]) & 0xFFFF0000u);
                    *(uint2*)(PwB + (st*16 + l16)*128
                              + (((2*ni + (quad >> 1)) ^ sw) * 16) + (quad & 1) * 8) = pk;
                }
            }

            // O += P V : A=P (m=q), B=Vt rows (n=d, k=ki); lacc += P * ones
#pragma unroll
            for (int ks = 0; ks < 2; ks++) {
                const int pco = ((4*ks + quad) ^ sw) * 16;
                short8 pf0 = *(const short8*)(PwB + (l16     )*128 + pco);
                short8 pf1 = *(const short8*)(PwB + (16 + l16)*128 + pco);
                lacc[0] = __builtin_amdgcn_mfma_f32_16x16x32_bf16(pf0, ones, lacc[0], 0, 0, 0);
                lacc[1] = __builtin_amdgcn_mfma_f32_16x16x32_bf16(pf1, ones, lacc[1], 0, 0, 0);
#pragma unroll
                for (int ni = 0; ni < 4; ni++) {
                    short8 vf = *(const short8*)(VcB + (ni*16 + l16)*128 + pco);
                    o_acc[0][ni] = __builtin_amdgcn_mfma_f32_16x16x32_bf16(pf0, vf, o_acc[0][ni], 0, 0, 0);
                    o_acc[1][ni] = __builtin_amdgcn_mfma_f32_16x16x32_bf16(pf1, vf, o_acc[1][ni], 0, 0, 0);
                }
            }

            par ^= 1;
        }

        // lacc[st][r] = row-sum for q = qb0 + w*32 + st*16 + quad*4 + r (all cols equal)
        float linv[2][4];
#pragma unroll
        for (int st = 0; st < 2; st++)
#pragma unroll
            for (int r = 0; r < 4; r++)
                linv[st][r] = 1.0f / lacc[st][r];

        u16* Ob = O + ((size_t)b * CTX) * EMBED + (size_t)h * HD;
#pragma unroll
        for (int st = 0; st < 2; st++)
#pragma unroll
            for (int ni = 0; ni < 4; ni++)
#pragma unroll
                for (int r = 0; r < 4; r++) {
                    const int qrow = qb0 + w*32 + st*16 + quad*4 + r;
                    Ob[(size_t)qrow * EMBED + ni*16 + l16] = f2bf(o_acc[st][ni][r] * linv[st][r]);
                }
    }
}

// ---------------- launcher ----------------
extern "C" void kernel_launch(void* const* d_in, const int* in_sizes, int n_in,
                              void* d_out, int out_size, void* d_ws, size_t ws_size,
                              hipStream_t stream) {
    const float* x  = (const float*)d_in[0];
    const float* Wq = (const float*)d_in[1];
    const float* bq = (const float*)d_in[2];
    const float* Wk = (const float*)d_in[3];
    const float* bk = (const float*)d_in[4];
    const float* Wv = (const float*)d_in[5];
    const float* bv = (const float*)d_in[6];
    const float* Wp = (const float*)d_in[7];
    const float* bp = (const float*)d_in[8];

    char* ws = (char*)d_ws;
    const size_t XSZ = (size_t)M_TOT * EMBED * 2;   // 16 MB
    const size_t WSZ = (size_t)EMBED * EMBED * 2;   // 2 MB
    u16* xb  = (u16*)ws;                 ws += XSZ;
    u16* wqb = (u16*)ws;                 ws += WSZ;
    u16* wkb = (u16*)ws;                 ws += WSZ;
    u16* wvb = (u16*)ws;                 ws += WSZ;
    u16* wpb = (u16*)ws;                 ws += WSZ;
    u16* qg  = (u16*)ws;                 ws += XSZ;
    u16* kg  = (u16*)ws;                 ws += XSZ;
    u16* vtg = (u16*)ws;                 ws += XSZ;
    u16* og  = xb;   // x-bf16 dead after QKV GEMM; attn output reuses it

    cvt_all<<<12288, 256, 0, stream>>>(x, Wq, Wk, Wv, Wp, xb, wqb, wkb, wvb, wpb);

    const float qscale = 0.125f * 1.44269504f;  // 1/sqrt(64) * log2(e)
    gemm_qkv<<<dim3(M_TOT/128, 24), 256, 0, stream>>>(xb, wqb, wkb, wvb, bq, bk, bv,
                                                      qg, kg, vtg, qscale);

    attn_kernel<<<dim3(512), 256, 0, stream>>>(qg, kg, vtg, og);

    gemm_proj<<<dim3(M_TOT/128, EMBED/64), 256, 0, stream>>>(og, wpb, bp, (float*)d_out);
}

// Round 7
// 262.894 us; speedup vs baseline: 1.0503x; 1.0503x over previous
//
#include <hip/hip_runtime.h>
#include <hip/hip_bf16.h>
#include <stdint.h>

#define EMBED 1024
#define HEADS 16
#define CTX   2048
#define BATCH 4
#define HD    64
#define M_TOT (BATCH*CTX)   // 8192

typedef unsigned short u16;
typedef __attribute__((ext_vector_type(8))) short short8;   // 8 bf16 (4 VGPRs)
typedef __attribute__((ext_vector_type(4))) float floatx4;  // MFMA C/D

typedef const __attribute__((address_space(1))) unsigned int g_u32;
typedef __attribute__((address_space(3))) unsigned int l_u32;

__device__ __forceinline__ void async16(const void* g, void* l) {
    __builtin_amdgcn_global_load_lds((g_u32*)g, (l_u32*)l, 16, 0, 0);
}

__device__ __forceinline__ u16 f2bf(float f) {          // round-nearest-even
    uint32_t u = __float_as_uint(f);
    uint32_t r = (u + 0x7FFFu + ((u >> 16) & 1u)) >> 16;
    return (u16)r;
}

// ---------------- fused fp32 -> bf16 convert (x + 4 weight matrices, 1 launch) ----------------
__global__ void cvt_all(const float* __restrict__ x,
                        const float* __restrict__ Wq, const float* __restrict__ Wk,
                        const float* __restrict__ Wv, const float* __restrict__ Wp,
                        u16* __restrict__ xb,
                        u16* __restrict__ wqb, u16* __restrict__ wkb,
                        u16* __restrict__ wvb, u16* __restrict__ wpb) {
    const int b = blockIdx.x;
    const float* src; u16* dst; int base;
    if (b < 8192)       { src = x;  dst = xb;  base = b; }
    else if (b < 9216)  { src = Wq; dst = wqb; base = b - 8192; }
    else if (b < 10240) { src = Wk; dst = wkb; base = b - 9216; }
    else if (b < 11264) { src = Wv; dst = wvb; base = b - 10240; }
    else                { src = Wp; dst = wpb; base = b - 11264; }
    const int i = (base * 256 + threadIdx.x) * 4;
    float4 f = *(const float4*)(src + i);
    ushort4 o;
    o.x = f2bf(f.x); o.y = f2bf(f.y); o.z = f2bf(f.z); o.w = f2bf(f.w);
    *(ushort4*)(dst + i) = o;
}

// ================= fused QKV GEMM, 128x128 tile, BK=64 (R0-verified structure) =================
__global__ __launch_bounds__(256)
void gemm_qkv(const u16* __restrict__ A,
              const u16* __restrict__ Wq, const u16* __restrict__ Wk, const u16* __restrict__ Wv,
              const float* __restrict__ bq, const float* __restrict__ bk, const float* __restrict__ bv,
              u16* __restrict__ oq, u16* __restrict__ ok, u16* __restrict__ ov,
              float qscale)
{
    __shared__ u16 As[128*64];   // 16 KB
    __shared__ u16 Bs[128*64];   // 16 KB
    const int tid  = threadIdx.x;
    const int lane = tid & 63;
    const int wid  = tid >> 6;
    const int wm = wid >> 1, wn = wid & 1;
    const int quad = lane >> 4;
    const int l16  = lane & 15;
    const int bm0 = blockIdx.x * 128;
    const int sel = blockIdx.y >> 3;          // 0=Q 1=K 2=V
    const int bn0 = (blockIdx.y & 7) * 128;

    const u16*  Bw   = (sel == 0) ? Wq : (sel == 1) ? Wk : Wv;
    const float* bias = (sel == 0) ? bq : (sel == 1) ? bk : bv;
    u16*        out  = (sel == 0) ? oq : (sel == 1) ? ok : ov;
    const float scale = (sel == 0) ? qscale : 1.0f;

    floatx4 acc[4][4] = {};

    const int r0   = tid >> 3;
    const int joff = ((tid & 7) ^ ((tid >> 3) & 7)) * 8;   // shorts
    const u16* Ag0 = A  + (size_t)(bm0 + r0      ) * EMBED + joff;
    const u16* Ag1 = A  + (size_t)(bm0 + r0 + 32 ) * EMBED + joff;
    const u16* Ag2 = A  + (size_t)(bm0 + r0 + 64 ) * EMBED + joff;
    const u16* Ag3 = A  + (size_t)(bm0 + r0 + 96 ) * EMBED + joff;
    const u16* Bg0 = Bw + (size_t)(bn0 + r0      ) * EMBED + joff;
    const u16* Bg1 = Bw + (size_t)(bn0 + r0 + 32 ) * EMBED + joff;
    const u16* Bg2 = Bw + (size_t)(bn0 + r0 + 64 ) * EMBED + joff;
    const u16* Bg3 = Bw + (size_t)(bn0 + r0 + 96 ) * EMBED + joff;
    char* AsB = (char*)As;
    char* BsB = (char*)Bs;
    const int wbyte = wid * 1024;

    const int fpos0 = (quad ^ (l16 & 7)) * 8;
    const int fpos1 = fpos0 ^ 32;

    for (int kk = 0; kk < EMBED; kk += 64) {
        __syncthreads();
        async16(Ag0 + kk, AsB + wbyte);
        async16(Ag1 + kk, AsB + wbyte + 4096);
        async16(Ag2 + kk, AsB + wbyte + 8192);
        async16(Ag3 + kk, AsB + wbyte + 12288);
        async16(Bg0 + kk, BsB + wbyte);
        async16(Bg1 + kk, BsB + wbyte + 4096);
        async16(Bg2 + kk, BsB + wbyte + 8192);
        async16(Bg3 + kk, BsB + wbyte + 12288);
        __syncthreads();

#pragma unroll
        for (int ks = 0; ks < 2; ks++) {
            const int fp = ks ? fpos1 : fpos0;
            short8 a[4], b[4];
#pragma unroll
            for (int i = 0; i < 4; i++)
                a[i] = *(const short8*)(As + (wm*64 + i*16 + l16)*64 + fp);
#pragma unroll
            for (int i = 0; i < 4; i++)
                b[i] = *(const short8*)(Bs + (wn*64 + i*16 + l16)*64 + fp);
#pragma unroll
            for (int i = 0; i < 4; i++)
#pragma unroll
                for (int j = 0; j < 4; j++)
                    acc[i][j] = __builtin_amdgcn_mfma_f32_16x16x32_bf16(a[i], b[j], acc[i][j], 0, 0, 0);
        }
    }

#pragma unroll
    for (int i = 0; i < 4; i++) {
#pragma unroll
        for (int j = 0; j < 4; j++) {
            const int col = bn0 + wn*64 + j*16 + l16;
            const float bvv = bias[col];
#pragma unroll
            for (int r = 0; r < 4; r++) {
                const int row = bm0 + wm*64 + i*16 + quad*4 + r;
                const float v = (acc[i][j][r] + bvv) * scale;
                const int bb = row >> 11, t = row & 2047;
                const int hh = col >> 6,  d = col & 63;
                if (sel != 2)
                    out[((size_t)(bb*HEADS + hh)*CTX + t)*HD + d] = f2bf(v);
                else
                    out[((size_t)(bb*HEADS + hh)*HD + d)*CTX + t] = f2bf(v);
            }
        }
    }
}

// ================= projection GEMM (fp32 out), BK=64 (R3-verified single-buffer) =================
__global__ __launch_bounds__(256)
void gemm_proj(const u16* __restrict__ A, const u16* __restrict__ Bw,
               const float* __restrict__ bias, float* __restrict__ out)
{
    __shared__ u16 As[128*64];
    __shared__ u16 Bs[128*64];
    const int tid  = threadIdx.x;
    const int lane = tid & 63;
    const int wid  = tid >> 6;
    const int wm = wid >> 1, wn = wid & 1;
    const int quad = lane >> 4;
    const int l16  = lane & 15;
    const int bm0 = blockIdx.x * 128;
    const int bn0 = blockIdx.y * 128;

    floatx4 acc[4][4] = {};

    const int r0   = tid >> 3;
    const int joff = ((tid & 7) ^ ((tid >> 3) & 7)) * 8;
    const u16* Ag0 = A  + (size_t)(bm0 + r0      ) * EMBED + joff;
    const u16* Ag1 = A  + (size_t)(bm0 + r0 + 32 ) * EMBED + joff;
    const u16* Ag2 = A  + (size_t)(bm0 + r0 + 64 ) * EMBED + joff;
    const u16* Ag3 = A  + (size_t)(bm0 + r0 + 96 ) * EMBED + joff;
    const u16* Bg0 = Bw + (size_t)(bn0 + r0      ) * EMBED + joff;
    const u16* Bg1 = Bw + (size_t)(bn0 + r0 + 32 ) * EMBED + joff;
    const u16* Bg2 = Bw + (size_t)(bn0 + r0 + 64 ) * EMBED + joff;
    const u16* Bg3 = Bw + (size_t)(bn0 + r0 + 96 ) * EMBED + joff;
    char* AsB = (char*)As;
    char* BsB = (char*)Bs;
    const int wbyte = wid * 1024;
    const int fpos0 = (quad ^ (l16 & 7)) * 8;
    const int fpos1 = fpos0 ^ 32;

    for (int kk = 0; kk < EMBED; kk += 64) {
        __syncthreads();
        async16(Ag0 + kk, AsB + wbyte);
        async16(Ag1 + kk, AsB + wbyte + 4096);
        async16(Ag2 + kk, AsB + wbyte + 8192);
        async16(Ag3 + kk, AsB + wbyte + 12288);
        async16(Bg0 + kk, BsB + wbyte);
        async16(Bg1 + kk, BsB + wbyte + 4096);
        async16(Bg2 + kk, BsB + wbyte + 8192);
        async16(Bg3 + kk, BsB + wbyte + 12288);
        __syncthreads();

#pragma unroll
        for (int ks = 0; ks < 2; ks++) {
            const int fp = ks ? fpos1 : fpos0;
            short8 a[4], b[4];
#pragma unroll
            for (int i = 0; i < 4; i++)
                a[i] = *(const short8*)(As + (wm*64 + i*16 + l16)*64 + fp);
#pragma unroll
            for (int i = 0; i < 4; i++)
                b[i] = *(const short8*)(Bs + (wn*64 + i*16 + l16)*64 + fp);
#pragma unroll
            for (int i = 0; i < 4; i++)
#pragma unroll
                for (int j = 0; j < 4; j++)
                    acc[i][j] = __builtin_amdgcn_mfma_f32_16x16x32_bf16(a[i], b[j], acc[i][j], 0, 0, 0);
        }
    }

#pragma unroll
    for (int i = 0; i < 4; i++) {
#pragma unroll
        for (int j = 0; j < 4; j++) {
            const int col = bn0 + wn*64 + j*16 + l16;
            const float bvv = bias[col];
#pragma unroll
            for (int r = 0; r < 4; r++) {
                const int row = bm0 + wm*64 + i*16 + quad*4 + r;
                out[(size_t)row * EMBED + col] = acc[i][j][r] + bvv;
            }
        }
    }
}

// ---------------- flash attention: 128 q/block, S^T order, swizzled P, MFMA row-sum ----------------
// R0-verified 128q structure. lsum via ones-MFMA: lacc[st] = mfma(pf, ONES, lacc)
// gives row-sums replicated across cols in the C-layout (reg r <-> q=quad*4+r) --
// exactly the indexing the O-write uses, so the end-of-pass shuffles vanish.
__global__ __launch_bounds__(256)
void attn_kernel(const u16* __restrict__ Q, const u16* __restrict__ K,
                 const u16* __restrict__ Vt, u16* __restrict__ O)
{
    __shared__ u16 Ks[2][64*64];     // 2 x 8 KB
    __shared__ u16 Vs[2][64*64];     // 2 x 8 KB   Vs[d][ki]
    __shared__ u16 Ps[4*32*64];      // 16 KB, per-wave 32 rows x 64 ki

    const int tid  = threadIdx.x, lane = tid & 63, w = tid >> 6;
    const int quad = lane >> 4, l16 = lane & 15;

    const int lid  = blockIdx.x;            // 0..511
    const int xcd  = lid & 7;
    const int slot = lid >> 3;              // 0..63
    const int bh   = xcd * 8 + (slot >> 3);
    const int bx   = slot & 7;              // 0..7
    const int h    = bh & (HEADS - 1);
    const int b    = bh >> 4;

    const u16* Qh = Q  + (size_t)bh * CTX * HD;
    const u16* Kh = K  + (size_t)bh * CTX * HD;
    const u16* Vh = Vt + (size_t)bh * HD * CTX;

    const int srow = tid >> 3;
    const int joff = ((tid & 7) ^ (srow & 7)) * 8;
    const int wbyte = w * 1024;
    char* PwB = (char*)(Ps + w * 32 * 64);
    const int sw = l16 & 7;                 // swizzle key (row&7 for all our rows)

    short8 ones;                            // bf16 1.0 x8
#pragma unroll
    for (int i = 0; i < 8; i++) ones[i] = (short)0x3F80;

    auto stage = [&](int kt, int buf) {
        char* kb = (char*)(&Ks[buf][0]) + wbyte;
        char* vb = (char*)(&Vs[buf][0]) + wbyte;
        async16(Kh + (size_t)(kt*64 + srow     )*HD + joff, kb);
        async16(Kh + (size_t)(kt*64 + srow + 32)*HD + joff, kb + 4096);
        async16(Vh + (size_t)(srow     )*CTX + kt*64 + joff, vb);
        async16(Vh + (size_t)(srow + 32)*CTX + kt*64 + joff, vb + 4096);
    };

    int par = 0;
    stage(0, 0);

#pragma unroll 1
    for (int pass = 0; pass < 2; pass++) {
        const int qb  = (pass == 0) ? bx : (15 - bx);
        const int qb0 = qb * 128;
        const int KT  = 2*qb + 2;

        // Q fragments (B-operand: n=q=l16, k=d): qf[subtile][kstep]
        short8 qf[2][2];
#pragma unroll
        for (int st = 0; st < 2; st++)
#pragma unroll
            for (int ks = 0; ks < 2; ks++)
                qf[st][ks] = *(const short8*)(Qh + (size_t)(qb0 + w*32 + st*16 + l16)*HD
                                              + ks*32 + quad*8);

        floatx4 lacc[2] = {};        // row-sum accumulators (ones-MFMA)
        floatx4 o_acc[2][4] = {};

        for (int kt = 0; kt < KT; kt++) {
            __syncthreads();   // drains stage(kt), in flight since previous compute

            if (kt + 1 < KT)      stage(kt + 1, par ^ 1);
            else if (pass == 0)   stage(0,      par ^ 1);

            const char* KcB = (const char*)(&Ks[par][0]);
            const char* VcB = (const char*)(&Vs[par][0]);

            // S^T = K Q^T : m=ki (row=quad*4+r), n=q (col=l16)
            floatx4 s[2][4] = {};
#pragma unroll
            for (int ks = 0; ks < 2; ks++) {
#pragma unroll
                for (int ni = 0; ni < 4; ni++) {
                    short8 kf = *(const short8*)(KcB + (ni*16 + l16)*128
                                                 + (((4*ks + quad) ^ sw) * 16));
                    s[0][ni] = __builtin_amdgcn_mfma_f32_16x16x32_bf16(kf, qf[0][ks], s[0][ni], 0, 0, 0);
                    s[1][ni] = __builtin_amdgcn_mfma_f32_16x16x32_bf16(kf, qf[1][ks], s[1][ni], 0, 0, 0);
                }
            }

            // P = exp2(S'), mask on last two tiles, packed b64 stores to swizzled P
            const bool mt = (kt >= 2*qb);
            const int key0 = kt * 64;
#pragma unroll
            for (int st = 0; st < 2; st++) {
                const int qrow = qb0 + w*32 + st*16 + l16;
#pragma unroll
                for (int ni = 0; ni < 4; ni++) {
                    float p[4];
#pragma unroll
                    for (int r = 0; r < 4; r++) {
                        float v = s[st][ni][r];
                        if (mt) {
                            const int key = key0 + ni*16 + quad*4 + r;
                            if (key > qrow) v = -INFINITY;
                        }
                        p[r] = __builtin_amdgcn_exp2f(v);
                    }
                    uint2 pk;
                    pk.x = (__float_as_uint(p[0]) >> 16) | (__float_as_uint(p[1]) & 0xFFFF0000u);
                    pk.y = (__float_as_uint(p[2]) >> 16) | (__float_as_uint(p[3]) & 0xFFFF0000u);
                    *(uint2*)(PwB + (st*16 + l16)*128
                              + (((2*ni + (quad >> 1)) ^ sw) * 16) + (quad & 1) * 8) = pk;
                }
            }

            // O += P V : A=P (m=q), B=Vt rows (n=d, k=ki); lacc += P * ones
#pragma unroll
            for (int ks = 0; ks < 2; ks++) {
                const int pco = ((4*ks + quad) ^ sw) * 16;
                short8 pf0 = *(const short8*)(PwB + (l16     )*128 + pco);
                short8 pf1 = *(const short8*)(PwB + (16 + l16)*128 + pco);
                lacc[0] = __builtin_amdgcn_mfma_f32_16x16x32_bf16(pf0, ones, lacc[0], 0, 0, 0);
                lacc[1] = __builtin_amdgcn_mfma_f32_16x16x32_bf16(pf1, ones, lacc[1], 0, 0, 0);
#pragma unroll
                for (int ni = 0; ni < 4; ni++) {
                    short8 vf = *(const short8*)(VcB + (ni*16 + l16)*128 + pco);
                    o_acc[0][ni] = __builtin_amdgcn_mfma_f32_16x16x32_bf16(pf0, vf, o_acc[0][ni], 0, 0, 0);
                    o_acc[1][ni] = __builtin_amdgcn_mfma_f32_16x16x32_bf16(pf1, vf, o_acc[1][ni], 0, 0, 0);
                }
            }

            par ^= 1;
        }

        // lacc[st][r] = row-sum for q = qb0 + w*32 + st*16 + quad*4 + r (all cols equal)
        float linv[2][4];
#pragma unroll
        for (int st = 0; st < 2; st++)
#pragma unroll
            for (int r = 0; r < 4; r++)
                linv[st][r] = 1.0f / lacc[st][r];

        u16* Ob = O + ((size_t)b * CTX) * EMBED + (size_t)h * HD;
#pragma unroll
        for (int st = 0; st < 2; st++)
#pragma unroll
            for (int ni = 0; ni < 4; ni++)
#pragma unroll
                for (int r = 0; r < 4; r++) {
                    const int qrow = qb0 + w*32 + st*16 + quad*4 + r;
                    Ob[(size_t)qrow * EMBED + ni*16 + l16] = f2bf(o_acc[st][ni][r] * linv[st][r]);
                }
    }
}

// ---------------- launcher ----------------
extern "C" void kernel_launch(void* const* d_in, const int* in_sizes, int n_in,
                              void* d_out, int out_size, void* d_ws, size_t ws_size,
                              hipStream_t stream) {
    const float* x  = (const float*)d_in[0];
    const float* Wq = (const float*)d_in[1];
    const float* bq = (const float*)d_in[2];
    const float* Wk = (const float*)d_in[3];
    const float* bk = (const float*)d_in[4];
    const float* Wv = (const float*)d_in[5];
    const float* bv = (const float*)d_in[6];
    const float* Wp = (const float*)d_in[7];
    const float* bp = (const float*)d_in[8];

    char* ws = (char*)d_ws;
    const size_t XSZ = (size_t)M_TOT * EMBED * 2;   // 16 MB
    const size_t WSZ = (size_t)EMBED * EMBED * 2;   // 2 MB
    u16* xb  = (u16*)ws;                 ws += XSZ;
    u16* wqb = (u16*)ws;                 ws += WSZ;
    u16* wkb = (u16*)ws;                 ws += WSZ;
    u16* wvb = (u16*)ws;                 ws += WSZ;
    u16* wpb = (u16*)ws;                 ws += WSZ;
    u16* qg  = (u16*)ws;                 ws += XSZ;
    u16* kg  = (u16*)ws;                 ws += XSZ;
    u16* vtg = (u16*)ws;                 ws += XSZ;
    u16* og  = xb;   // x-bf16 dead after QKV GEMM; attn output reuses it

    cvt_all<<<12288, 256, 0, stream>>>(x, Wq, Wk, Wv, Wp, xb, wqb, wkb, wvb, wpb);

    const float qscale = 0.125f * 1.44269504f;  // 1/sqrt(64) * log2(e)
    gemm_qkv<<<dim3(M_TOT/128, 24), 256, 0, stream>>>(xb, wqb, wkb, wvb, bq, bk, bv,
                                                      qg, kg, vtg, qscale);

    attn_kernel<<<dim3(512), 256, 0, stream>>>(qg, kg, vtg, og);

    gemm_proj<<<dim3(M_TOT/128, EMBED/128), 256, 0, stream>>>(og, wpb, bp, (float*)d_out);
}

// Round 12
// 259.836 us; speedup vs baseline: 1.0626x; 1.0118x over previous
//
#include <hip/hip_runtime.h>
#include <hip/hip_bf16.h>
#include <stdint.h>

#define EMBED 1024
#define HEADS 16
#define CTX   2048
#define BATCH 4
#define HD    64
#define M_TOT (BATCH*CTX)   // 8192

typedef unsigned short u16;
typedef __attribute__((ext_vector_type(8))) short short8;   // 8 bf16 (4 VGPRs)
typedef __attribute__((ext_vector_type(4))) float floatx4;  // MFMA C/D

typedef const __attribute__((address_space(1))) unsigned int g_u32;
typedef __attribute__((address_space(3))) unsigned int l_u32;

__device__ __forceinline__ void async16(const void* g, void* l) {
    __builtin_amdgcn_global_load_lds((g_u32*)g, (l_u32*)l, 16, 0, 0);
}

__device__ __forceinline__ u16 f2bf(float f) {          // round-nearest-even
    uint32_t u = __float_as_uint(f);
    uint32_t r = (u + 0x7FFFu + ((u >> 16) & 1u)) >> 16;
    return (u16)r;
}

// ---------------- fused fp32 -> bf16 convert (x + 4 weight matrices, 1 launch) ----------------
__global__ void cvt_all(const float* __restrict__ x,
                        const float* __restrict__ Wq, const float* __restrict__ Wk,
                        const float* __restrict__ Wv, const float* __restrict__ Wp,
                        u16* __restrict__ xb,
                        u16* __restrict__ wqb, u16* __restrict__ wkb,
                        u16* __restrict__ wvb, u16* __restrict__ wpb) {
    const int b = blockIdx.x;
    const float* src; u16* dst; int base;
    if (b < 8192)       { src = x;  dst = xb;  base = b; }
    else if (b < 9216)  { src = Wq; dst = wqb; base = b - 8192; }
    else if (b < 10240) { src = Wk; dst = wkb; base = b - 9216; }
    else if (b < 11264) { src = Wv; dst = wvb; base = b - 10240; }
    else                { src = Wp; dst = wpb; base = b - 11264; }
    const int i = (base * 256 + threadIdx.x) * 4;
    float4 f = *(const float4*)(src + i);
    ushort4 o;
    o.x = f2bf(f.x); o.y = f2bf(f.y); o.z = f2bf(f.z); o.w = f2bf(f.w);
    *(ushort4*)(dst + i) = o;
}

// ================= fused QKV GEMM, 128x128 tile, BK=64 (R0-verified structure) =================
__global__ __launch_bounds__(256)
void gemm_qkv(const u16* __restrict__ A,
              const u16* __restrict__ Wq, const u16* __restrict__ Wk, const u16* __restrict__ Wv,
              const float* __restrict__ bq, const float* __restrict__ bk, const float* __restrict__ bv,
              u16* __restrict__ oq, u16* __restrict__ ok, u16* __restrict__ ov,
              float qscale)
{
    __shared__ u16 As[128*64];   // 16 KB
    __shared__ u16 Bs[128*64];   // 16 KB
    const int tid  = threadIdx.x;
    const int lane = tid & 63;
    const int wid  = tid >> 6;
    const int wm = wid >> 1, wn = wid & 1;
    const int quad = lane >> 4;
    const int l16  = lane & 15;
    const int bm0 = blockIdx.x * 128;
    const int sel = blockIdx.y >> 3;          // 0=Q 1=K 2=V
    const int bn0 = (blockIdx.y & 7) * 128;

    const u16*  Bw   = (sel == 0) ? Wq : (sel == 1) ? Wk : Wv;
    const float* bias = (sel == 0) ? bq : (sel == 1) ? bk : bv;
    u16*        out  = (sel == 0) ? oq : (sel == 1) ? ok : ov;
    const float scale = (sel == 0) ? qscale : 1.0f;

    floatx4 acc[4][4] = {};

    const int r0   = tid >> 3;
    const int joff = ((tid & 7) ^ ((tid >> 3) & 7)) * 8;   // shorts
    const u16* Ag0 = A  + (size_t)(bm0 + r0      ) * EMBED + joff;
    const u16* Ag1 = A  + (size_t)(bm0 + r0 + 32 ) * EMBED + joff;
    const u16* Ag2 = A  + (size_t)(bm0 + r0 + 64 ) * EMBED + joff;
    const u16* Ag3 = A  + (size_t)(bm0 + r0 + 96 ) * EMBED + joff;
    const u16* Bg0 = Bw + (size_t)(bn0 + r0      ) * EMBED + joff;
    const u16* Bg1 = Bw + (size_t)(bn0 + r0 + 32 ) * EMBED + joff;
    const u16* Bg2 = Bw + (size_t)(bn0 + r0 + 64 ) * EMBED + joff;
    const u16* Bg3 = Bw + (size_t)(bn0 + r0 + 96 ) * EMBED + joff;
    char* AsB = (char*)As;
    char* BsB = (char*)Bs;
    const int wbyte = wid * 1024;

    const int fpos0 = (quad ^ (l16 & 7)) * 8;
    const int fpos1 = fpos0 ^ 32;

    for (int kk = 0; kk < EMBED; kk += 64) {
        __syncthreads();
        async16(Ag0 + kk, AsB + wbyte);
        async16(Ag1 + kk, AsB + wbyte + 4096);
        async16(Ag2 + kk, AsB + wbyte + 8192);
        async16(Ag3 + kk, AsB + wbyte + 12288);
        async16(Bg0 + kk, BsB + wbyte);
        async16(Bg1 + kk, BsB + wbyte + 4096);
        async16(Bg2 + kk, BsB + wbyte + 8192);
        async16(Bg3 + kk, BsB + wbyte + 12288);
        __syncthreads();

#pragma unroll
        for (int ks = 0; ks < 2; ks++) {
            const int fp = ks ? fpos1 : fpos0;
            short8 a[4], b[4];
#pragma unroll
            for (int i = 0; i < 4; i++)
                a[i] = *(const short8*)(As + (wm*64 + i*16 + l16)*64 + fp);
#pragma unroll
            for (int i = 0; i < 4; i++)
                b[i] = *(const short8*)(Bs + (wn*64 + i*16 + l16)*64 + fp);
#pragma unroll
            for (int i = 0; i < 4; i++)
#pragma unroll
                for (int j = 0; j < 4; j++)
                    acc[i][j] = __builtin_amdgcn_mfma_f32_16x16x32_bf16(a[i], b[j], acc[i][j], 0, 0, 0);
        }
    }

#pragma unroll
    for (int i = 0; i < 4; i++) {
#pragma unroll
        for (int j = 0; j < 4; j++) {
            const int col = bn0 + wn*64 + j*16 + l16;
            const float bvv = bias[col];
#pragma unroll
            for (int r = 0; r < 4; r++) {
                const int row = bm0 + wm*64 + i*16 + quad*4 + r;
                const float v = (acc[i][j][r] + bvv) * scale;
                const int bb = row >> 11, t = row & 2047;
                const int hh = col >> 6,  d = col & 63;
                if (sel != 2)
                    out[((size_t)(bb*HEADS + hh)*CTX + t)*HD + d] = f2bf(v);
                else
                    out[((size_t)(bb*HEADS + hh)*HD + d)*CTX + t] = f2bf(v);
            }
        }
    }
}

// ================= projection GEMM (fp32 out), 128x128, intra-block split-K =================
// 512 threads = 2 groups x 4 waves. Group g computes K in [g*512, g*512+512) with
// the byte-identical verified 128x128x64 staging+MFMA iteration on its own 32 KB
// LDS pair (S[2g], S[2g+1]). Grid stays 512 (grid-limited to 2 blocks/CU); this
// doubles waves/CU 8->16 and halves the per-block count of exposed staging stalls
// (8 iters of 2x compute vs 16 of 1x). Epilogue: group1 acc -> LDS (lane-stride
// layout, conflict-free), group0 adds + bias + stores. No combine kernel.
__global__ __launch_bounds__(512, 4)
void gemm_proj(const u16* __restrict__ A, const u16* __restrict__ Bw,
               const float* __restrict__ bias, float* __restrict__ out)
{
    __shared__ u16 S[4][128*64];   // 64 KB: group g uses S[2g]=A-tile, S[2g+1]=B-tile
    const int tid  = threadIdx.x;
    const int t    = tid & 255;          // intra-group thread id (mirrors old tid)
    const int g    = tid >> 8;           // K-half group 0/1
    const int lane = t & 63;
    const int wid  = t >> 6;
    const int wm = wid >> 1, wn = wid & 1;
    const int quad = lane >> 4;
    const int l16  = lane & 15;
    const int bm0 = blockIdx.x * 128;
    const int bn0 = blockIdx.y * 128;

    floatx4 acc[4][4] = {};

    const int r0   = t >> 3;
    const int joff = ((t & 7) ^ ((t >> 3) & 7)) * 8;
    const int kb   = g * 512;            // group K-base (shorts)
    const u16* Ag0 = A  + (size_t)(bm0 + r0      ) * EMBED + kb + joff;
    const u16* Ag1 = A  + (size_t)(bm0 + r0 + 32 ) * EMBED + kb + joff;
    const u16* Ag2 = A  + (size_t)(bm0 + r0 + 64 ) * EMBED + kb + joff;
    const u16* Ag3 = A  + (size_t)(bm0 + r0 + 96 ) * EMBED + kb + joff;
    const u16* Bg0 = Bw + (size_t)(bn0 + r0      ) * EMBED + kb + joff;
    const u16* Bg1 = Bw + (size_t)(bn0 + r0 + 32 ) * EMBED + kb + joff;
    const u16* Bg2 = Bw + (size_t)(bn0 + r0 + 64 ) * EMBED + kb + joff;
    const u16* Bg3 = Bw + (size_t)(bn0 + r0 + 96 ) * EMBED + kb + joff;
    const u16* Ac = &S[2*g][0];
    const u16* Bc = &S[2*g+1][0];
    char* AsB = (char*)Ac;
    char* BsB = (char*)Bc;
    const int wbyte = wid * 1024;
    const int fpos0 = (quad ^ (l16 & 7)) * 8;
    const int fpos1 = fpos0 ^ 32;

    for (int kk = 0; kk < 512; kk += 64) {
        __syncthreads();
        async16(Ag0 + kk, AsB + wbyte);
        async16(Ag1 + kk, AsB + wbyte + 4096);
        async16(Ag2 + kk, AsB + wbyte + 8192);
        async16(Ag3 + kk, AsB + wbyte + 12288);
        async16(Bg0 + kk, BsB + wbyte);
        async16(Bg1 + kk, BsB + wbyte + 4096);
        async16(Bg2 + kk, BsB + wbyte + 8192);
        async16(Bg3 + kk, BsB + wbyte + 12288);
        __syncthreads();

#pragma unroll
        for (int ks = 0; ks < 2; ks++) {
            const int fp = ks ? fpos1 : fpos0;
            short8 a[4], b[4];
#pragma unroll
            for (int i = 0; i < 4; i++)
                a[i] = *(const short8*)(Ac + (wm*64 + i*16 + l16)*64 + fp);
#pragma unroll
            for (int i = 0; i < 4; i++)
                b[i] = *(const short8*)(Bc + (wn*64 + i*16 + l16)*64 + fp);
#pragma unroll
            for (int i = 0; i < 4; i++)
#pragma unroll
                for (int j = 0; j < 4; j++)
                    acc[i][j] = __builtin_amdgcn_mfma_f32_16x16x32_bf16(a[i], b[j], acc[i][j], 0, 0, 0);
        }
    }

    // ---- cross-group K-reduce through LDS (64 KB = 16384 floats, exact fit) ----
    __syncthreads();                      // all waves done reading S
    float* X = (float*)&S[0][0];
    if (g == 1) {
#pragma unroll
        for (int i = 0; i < 4; i++)
#pragma unroll
            for (int j = 0; j < 4; j++)
#pragma unroll
                for (int r = 0; r < 4; r++)
                    X[((i*4 + j)*4 + r) * 256 + t] = acc[i][j][r];  // lane-stride: conflict-free
    }
    __syncthreads();
    if (g == 0) {
#pragma unroll
        for (int i = 0; i < 4; i++) {
#pragma unroll
            for (int j = 0; j < 4; j++) {
                const int col = bn0 + wn*64 + j*16 + l16;
                const float bvv = bias[col];
#pragma unroll
                for (int r = 0; r < 4; r++) {
                    const float v = acc[i][j][r] + X[((i*4 + j)*4 + r) * 256 + t] + bvv;
                    const int row = bm0 + wm*64 + i*16 + quad*4 + r;
                    out[(size_t)row * EMBED + col] = v;
                }
            }
        }
    }
}

// ---------------- flash attention: 128 q/block, S^T order, swizzled P, MFMA row-sum ----------------
// R0-verified 128q structure. lsum via ones-MFMA: lacc[st] = mfma(pf, ONES, lacc)
// gives row-sums replicated across cols in the C-layout (reg r <-> q=quad*4+r) --
// exactly the indexing the O-write uses, so the end-of-pass shuffles vanish.
__global__ __launch_bounds__(256)
void attn_kernel(const u16* __restrict__ Q, const u16* __restrict__ K,
                 const u16* __restrict__ Vt, u16* __restrict__ O)
{
    __shared__ u16 Ks[2][64*64];     // 2 x 8 KB
    __shared__ u16 Vs[2][64*64];     // 2 x 8 KB   Vs[d][ki]
    __shared__ u16 Ps[4*32*64];      // 16 KB, per-wave 32 rows x 64 ki

    const int tid  = threadIdx.x, lane = tid & 63, w = tid >> 6;
    const int quad = lane >> 4, l16 = lane & 15;

    const int lid  = blockIdx.x;            // 0..511
    const int xcd  = lid & 7;
    const int slot = lid >> 3;              // 0..63
    const int bh   = xcd * 8 + (slot >> 3);
    const int bx   = slot & 7;              // 0..7
    const int h    = bh & (HEADS - 1);
    const int b    = bh >> 4;

    const u16* Qh = Q  + (size_t)bh * CTX * HD;
    const u16* Kh = K  + (size_t)bh * CTX * HD;
    const u16* Vh = Vt + (size_t)bh * HD * CTX;

    const int srow = tid >> 3;
    const int joff = ((tid & 7) ^ (srow & 7)) * 8;
    const int wbyte = w * 1024;
    char* PwB = (char*)(Ps + w * 32 * 64);
    const int sw = l16 & 7;                 // swizzle key (row&7 for all our rows)

    short8 ones;                            // bf16 1.0 x8
#pragma unroll
    for (int i = 0; i < 8; i++) ones[i] = (short)0x3F80;

    auto stage = [&](int kt, int buf) {
        char* kb = (char*)(&Ks[buf][0]) + wbyte;
        char* vb = (char*)(&Vs[buf][0]) + wbyte;
        async16(Kh + (size_t)(kt*64 + srow     )*HD + joff, kb);
        async16(Kh + (size_t)(kt*64 + srow + 32)*HD + joff, kb + 4096);
        async16(Vh + (size_t)(srow     )*CTX + kt*64 + joff, vb);
        async16(Vh + (size_t)(srow + 32)*CTX + kt*64 + joff, vb + 4096);
    };

    int par = 0;
    stage(0, 0);

#pragma unroll 1
    for (int pass = 0; pass < 2; pass++) {
        const int qb  = (pass == 0) ? bx : (15 - bx);
        const int qb0 = qb * 128;
        const int KT  = 2*qb + 2;

        // Q fragments (B-operand: n=q=l16, k=d): qf[subtile][kstep]
        short8 qf[2][2];
#pragma unroll
        for (int st = 0; st < 2; st++)
#pragma unroll
            for (int ks = 0; ks < 2; ks++)
                qf[st][ks] = *(const short8*)(Qh + (size_t)(qb0 + w*32 + st*16 + l16)*HD
                                              + ks*32 + quad*8);

        floatx4 lacc[2] = {};        // row-sum accumulators (ones-MFMA)
        floatx4 o_acc[2][4] = {};

        for (int kt = 0; kt < KT; kt++) {
            __syncthreads();   // drains stage(kt), in flight since previous compute

            if (kt + 1 < KT)      stage(kt + 1, par ^ 1);
            else if (pass == 0)   stage(0,      par ^ 1);

            const char* KcB = (const char*)(&Ks[par][0]);
            const char* VcB = (const char*)(&Vs[par][0]);

            // S^T = K Q^T : m=ki (row=quad*4+r), n=q (col=l16)
            floatx4 s[2][4] = {};
#pragma unroll
            for (int ks = 0; ks < 2; ks++) {
#pragma unroll
                for (int ni = 0; ni < 4; ni++) {
                    short8 kf = *(const short8*)(KcB + (ni*16 + l16)*128
                                                 + (((4*ks + quad) ^ sw) * 16));
                    s[0][ni] = __builtin_amdgcn_mfma_f32_16x16x32_bf16(kf, qf[0][ks], s[0][ni], 0, 0, 0);
                    s[1][ni] = __builtin_amdgcn_mfma_f32_16x16x32_bf16(kf, qf[1][ks], s[1][ni], 0, 0, 0);
                }
            }

            // P = exp2(S'), mask on last two tiles, packed b64 stores to swizzled P
            const bool mt = (kt >= 2*qb);
            const int key0 = kt * 64;
#pragma unroll
            for (int st = 0; st < 2; st++) {
                const int qrow = qb0 + w*32 + st*16 + l16;
#pragma unroll
                for (int ni = 0; ni < 4; ni++) {
                    float p[4];
#pragma unroll
                    for (int r = 0; r < 4; r++) {
                        float v = s[st][ni][r];
                        if (mt) {
                            const int key = key0 + ni*16 + quad*4 + r;
                            if (key > qrow) v = -INFINITY;
                        }
                        p[r] = __builtin_amdgcn_exp2f(v);
                    }
                    uint2 pk;
                    pk.x = (__float_as_uint(p[0]) >> 16) | (__float_as_uint(p[1]) & 0xFFFF0000u);
                    pk.y = (__float_as_uint(p[2]) >> 16) | (__float_as_uint(p[3]) & 0xFFFF0000u);
                    *(uint2*)(PwB + (st*16 + l16)*128
                              + (((2*ni + (quad >> 1)) ^ sw) * 16) + (quad & 1) * 8) = pk;
                }
            }

            // O += P V : A=P (m=q), B=Vt rows (n=d, k=ki); lacc += P * ones
#pragma unroll
            for (int ks = 0; ks < 2; ks++) {
                const int pco = ((4*ks + quad) ^ sw) * 16;
                short8 pf0 = *(const short8*)(PwB + (l16     )*128 + pco);
                short8 pf1 = *(const short8*)(PwB + (16 + l16)*128 + pco);
                lacc[0] = __builtin_amdgcn_mfma_f32_16x16x32_bf16(pf0, ones, lacc[0], 0, 0, 0);
                lacc[1] = __builtin_amdgcn_mfma_f32_16x16x32_bf16(pf1, ones, lacc[1], 0, 0, 0);
#pragma unroll
                for (int ni = 0; ni < 4; ni++) {
                    short8 vf = *(const short8*)(VcB + (ni*16 + l16)*128 + pco);
                    o_acc[0][ni] = __builtin_amdgcn_mfma_f32_16x16x32_bf16(pf0, vf, o_acc[0][ni], 0, 0, 0);
                    o_acc[1][ni] = __builtin_amdgcn_mfma_f32_16x16x32_bf16(pf1, vf, o_acc[1][ni], 0, 0, 0);
                }
            }

            par ^= 1;
        }

        // lacc[st][r] = row-sum for q = qb0 + w*32 + st*16 + quad*4 + r (all cols equal)
        float linv[2][4];
#pragma unroll
        for (int st = 0; st < 2; st++)
#pragma unroll
            for (int r = 0; r < 4; r++)
                linv[st][r] = 1.0f / lacc[st][r];

        u16* Ob = O + ((size_t)b * CTX) * EMBED + (size_t)h * HD;
#pragma unroll
        for (int st = 0; st < 2; st++)
#pragma unroll
            for (int ni = 0; ni < 4; ni++)
#pragma unroll
                for (int r = 0; r < 4; r++) {
                    const int qrow = qb0 + w*32 + st*16 + quad*4 + r;
                    Ob[(size_t)qrow * EMBED + ni*16 + l16] = f2bf(o_acc[st][ni][r] * linv[st][r]);
                }
    }
}

// ---------------- launcher ----------------
extern "C" void kernel_launch(void* const* d_in, const int* in_sizes, int n_in,
                              void* d_out, int out_size, void* d_ws, size_t ws_size,
                              hipStream_t stream) {
    const float* x  = (const float*)d_in[0];
    const float* Wq = (const float*)d_in[1];
    const float* bq = (const float*)d_in[2];
    const float* Wk = (const float*)d_in[3];
    const float* bk = (const float*)d_in[4];
    const float* Wv = (const float*)d_in[5];
    const float* bv = (const float*)d_in[6];
    const float* Wp = (const float*)d_in[7];
    const float* bp = (const float*)d_in[8];

    char* ws = (char*)d_ws;
    const size_t XSZ = (size_t)M_TOT * EMBED * 2;   // 16 MB
    const size_t WSZ = (size_t)EMBED * EMBED * 2;   // 2 MB
    u16* xb  = (u16*)ws;                 ws += XSZ;
    u16* wqb = (u16*)ws;                 ws += WSZ;
    u16* wkb = (u16*)ws;                 ws += WSZ;
    u16* wvb = (u16*)ws;                 ws += WSZ;
    u16* wpb = (u16*)ws;                 ws += WSZ;
    u16* qg  = (u16*)ws;                 ws += XSZ;
    u16* kg  = (u16*)ws;                 ws += XSZ;
    u16* vtg = (u16*)ws;                 ws += XSZ;
    u16* og  = xb;   // x-bf16 dead after QKV GEMM; attn output reuses it

    cvt_all<<<12288, 256, 0, stream>>>(x, Wq, Wk, Wv, Wp, xb, wqb, wkb, wvb, wpb);

    const float qscale = 0.125f * 1.44269504f;  // 1/sqrt(64) * log2(e)
    gemm_qkv<<<dim3(M_TOT/128, 24), 256, 0, stream>>>(xb, wqb, wkb, wvb, bq, bk, bv,
                                                      qg, kg, vtg, qscale);

    attn_kernel<<<dim3(512), 256, 0, stream>>>(qg, kg, vtg, og);

    gemm_proj<<<dim3(M_TOT/128, EMBED/128), 512, 0, stream>>>(og, wpb, bp, (float*)d_out);
}

// Round 14
// 255.840 us; speedup vs baseline: 1.0792x; 1.0156x over previous
//
#include <hip/hip_runtime.h>
#include <hip/hip_bf16.h>
#include <stdint.h>

#define EMBED 1024
#define HEADS 16
#define CTX   2048
#define BATCH 4
#define HD    64
#define M_TOT (BATCH*CTX)   // 8192

typedef unsigned short u16;
typedef __attribute__((ext_vector_type(8))) short short8;   // 8 bf16 (4 VGPRs)
typedef __attribute__((ext_vector_type(4))) float floatx4;  // MFMA C/D

typedef const __attribute__((address_space(1))) unsigned int g_u32;
typedef __attribute__((address_space(3))) unsigned int l_u32;

__device__ __forceinline__ void async16(const void* g, void* l) {
    __builtin_amdgcn_global_load_lds((g_u32*)g, (l_u32*)l, 16, 0, 0);
}

__device__ __forceinline__ u16 f2bf(float f) {          // round-nearest-even
    uint32_t u = __float_as_uint(f);
    uint32_t r = (u + 0x7FFFu + ((u >> 16) & 1u)) >> 16;
    return (u16)r;
}

// ---------------- fused fp32 -> bf16 convert (x + 4 weight matrices, 1 launch) ----------------
__global__ void cvt_all(const float* __restrict__ x,
                        const float* __restrict__ Wq, const float* __restrict__ Wk,
                        const float* __restrict__ Wv, const float* __restrict__ Wp,
                        u16* __restrict__ xb,
                        u16* __restrict__ wqb, u16* __restrict__ wkb,
                        u16* __restrict__ wvb, u16* __restrict__ wpb) {
    const int b = blockIdx.x;
    const float* src; u16* dst; int base;
    if (b < 8192)       { src = x;  dst = xb;  base = b; }
    else if (b < 9216)  { src = Wq; dst = wqb; base = b - 8192; }
    else if (b < 10240) { src = Wk; dst = wkb; base = b - 9216; }
    else if (b < 11264) { src = Wv; dst = wvb; base = b - 10240; }
    else                { src = Wp; dst = wpb; base = b - 11264; }
    const int i = (base * 256 + threadIdx.x) * 4;
    float4 f = *(const float4*)(src + i);
    ushort4 o;
    o.x = f2bf(f.x); o.y = f2bf(f.y); o.z = f2bf(f.z); o.w = f2bf(f.w);
    *(ushort4*)(dst + i) = o;
}

// ================= fused QKV GEMM, 128x128 tile, BK=64 (R0-verified structure) =================
__global__ __launch_bounds__(256)
void gemm_qkv(const u16* __restrict__ A,
              const u16* __restrict__ Wq, const u16* __restrict__ Wk, const u16* __restrict__ Wv,
              const float* __restrict__ bq, const float* __restrict__ bk, const float* __restrict__ bv,
              u16* __restrict__ oq, u16* __restrict__ ok, u16* __restrict__ ov,
              float qscale)
{
    __shared__ u16 As[128*64];   // 16 KB
    __shared__ u16 Bs[128*64];   // 16 KB
    const int tid  = threadIdx.x;
    const int lane = tid & 63;
    const int wid  = tid >> 6;
    const int wm = wid >> 1, wn = wid & 1;
    const int quad = lane >> 4;
    const int l16  = lane & 15;
    const int bm0 = blockIdx.x * 128;
    const int sel = blockIdx.y >> 3;          // 0=Q 1=K 2=V
    const int bn0 = (blockIdx.y & 7) * 128;

    const u16*  Bw   = (sel == 0) ? Wq : (sel == 1) ? Wk : Wv;
    const float* bias = (sel == 0) ? bq : (sel == 1) ? bk : bv;
    u16*        out  = (sel == 0) ? oq : (sel == 1) ? ok : ov;
    const float scale = (sel == 0) ? qscale : 1.0f;

    floatx4 acc[4][4] = {};

    const int r0   = tid >> 3;
    const int joff = ((tid & 7) ^ ((tid >> 3) & 7)) * 8;   // shorts
    const u16* Ag0 = A  + (size_t)(bm0 + r0      ) * EMBED + joff;
    const u16* Ag1 = A  + (size_t)(bm0 + r0 + 32 ) * EMBED + joff;
    const u16* Ag2 = A  + (size_t)(bm0 + r0 + 64 ) * EMBED + joff;
    const u16* Ag3 = A  + (size_t)(bm0 + r0 + 96 ) * EMBED + joff;
    const u16* Bg0 = Bw + (size_t)(bn0 + r0      ) * EMBED + joff;
    const u16* Bg1 = Bw + (size_t)(bn0 + r0 + 32 ) * EMBED + joff;
    const u16* Bg2 = Bw + (size_t)(bn0 + r0 + 64 ) * EMBED + joff;
    const u16* Bg3 = Bw + (size_t)(bn0 + r0 + 96 ) * EMBED + joff;
    char* AsB = (char*)As;
    char* BsB = (char*)Bs;
    const int wbyte = wid * 1024;

    const int fpos0 = (quad ^ (l16 & 7)) * 8;
    const int fpos1 = fpos0 ^ 32;

    for (int kk = 0; kk < EMBED; kk += 64) {
        __syncthreads();
        async16(Ag0 + kk, AsB + wbyte);
        async16(Ag1 + kk, AsB + wbyte + 4096);
        async16(Ag2 + kk, AsB + wbyte + 8192);
        async16(Ag3 + kk, AsB + wbyte + 12288);
        async16(Bg0 + kk, BsB + wbyte);
        async16(Bg1 + kk, BsB + wbyte + 4096);
        async16(Bg2 + kk, BsB + wbyte + 8192);
        async16(Bg3 + kk, BsB + wbyte + 12288);
        __syncthreads();

#pragma unroll
        for (int ks = 0; ks < 2; ks++) {
            const int fp = ks ? fpos1 : fpos0;
            short8 a[4], b[4];
#pragma unroll
            for (int i = 0; i < 4; i++)
                a[i] = *(const short8*)(As + (wm*64 + i*16 + l16)*64 + fp);
#pragma unroll
            for (int i = 0; i < 4; i++)
                b[i] = *(const short8*)(Bs + (wn*64 + i*16 + l16)*64 + fp);
#pragma unroll
            for (int i = 0; i < 4; i++)
#pragma unroll
                for (int j = 0; j < 4; j++)
                    acc[i][j] = __builtin_amdgcn_mfma_f32_16x16x32_bf16(a[i], b[j], acc[i][j], 0, 0, 0);
        }
    }

#pragma unroll
    for (int i = 0; i < 4; i++) {
#pragma unroll
        for (int j = 0; j < 4; j++) {
            const int col = bn0 + wn*64 + j*16 + l16;
            const float bvv = bias[col];
#pragma unroll
            for (int r = 0; r < 4; r++) {
                const int row = bm0 + wm*64 + i*16 + quad*4 + r;
                const float v = (acc[i][j][r] + bvv) * scale;
                const int bb = row >> 11, t = row & 2047;
                const int hh = col >> 6,  d = col & 63;
                if (sel != 2)
                    out[((size_t)(bb*HEADS + hh)*CTX + t)*HD + d] = f2bf(v);
                else
                    out[((size_t)(bb*HEADS + hh)*HD + d)*CTX + t] = f2bf(v);
            }
        }
    }
}

// ================= projection GEMM (fp32 out), 128x128, intra-block split-K =================
// (R12-measured best: 512 threads = 2 groups x 4 waves, group g covers K half,
// own 32 KB LDS pair; LDS-exchange epilogue. ~-3 us vs single-group.)
__global__ __launch_bounds__(512, 4)
void gemm_proj(const u16* __restrict__ A, const u16* __restrict__ Bw,
               const float* __restrict__ bias, float* __restrict__ out)
{
    __shared__ u16 S[4][128*64];   // 64 KB: group g uses S[2g]=A-tile, S[2g+1]=B-tile
    const int tid  = threadIdx.x;
    const int t    = tid & 255;          // intra-group thread id (mirrors old tid)
    const int g    = tid >> 8;           // K-half group 0/1
    const int lane = t & 63;
    const int wid  = t >> 6;
    const int wm = wid >> 1, wn = wid & 1;
    const int quad = lane >> 4;
    const int l16  = lane & 15;
    const int bm0 = blockIdx.x * 128;
    const int bn0 = blockIdx.y * 128;

    floatx4 acc[4][4] = {};

    const int r0   = t >> 3;
    const int joff = ((t & 7) ^ ((t >> 3) & 7)) * 8;
    const int kb   = g * 512;            // group K-base (shorts)
    const u16* Ag0 = A  + (size_t)(bm0 + r0      ) * EMBED + kb + joff;
    const u16* Ag1 = A  + (size_t)(bm0 + r0 + 32 ) * EMBED + kb + joff;
    const u16* Ag2 = A  + (size_t)(bm0 + r0 + 64 ) * EMBED + kb + joff;
    const u16* Ag3 = A  + (size_t)(bm0 + r0 + 96 ) * EMBED + kb + joff;
    const u16* Bg0 = Bw + (size_t)(bn0 + r0      ) * EMBED + kb + joff;
    const u16* Bg1 = Bw + (size_t)(bn0 + r0 + 32 ) * EMBED + kb + joff;
    const u16* Bg2 = Bw + (size_t)(bn0 + r0 + 64 ) * EMBED + kb + joff;
    const u16* Bg3 = Bw + (size_t)(bn0 + r0 + 96 ) * EMBED + kb + joff;
    const u16* Ac = &S[2*g][0];
    const u16* Bc = &S[2*g+1][0];
    char* AsB = (char*)Ac;
    char* BsB = (char*)Bc;
    const int wbyte = wid * 1024;
    const int fpos0 = (quad ^ (l16 & 7)) * 8;
    const int fpos1 = fpos0 ^ 32;

    for (int kk = 0; kk < 512; kk += 64) {
        __syncthreads();
        async16(Ag0 + kk, AsB + wbyte);
        async16(Ag1 + kk, AsB + wbyte + 4096);
        async16(Ag2 + kk, AsB + wbyte + 8192);
        async16(Ag3 + kk, AsB + wbyte + 12288);
        async16(Bg0 + kk, BsB + wbyte);
        async16(Bg1 + kk, BsB + wbyte + 4096);
        async16(Bg2 + kk, BsB + wbyte + 8192);
        async16(Bg3 + kk, BsB + wbyte + 12288);
        __syncthreads();

#pragma unroll
        for (int ks = 0; ks < 2; ks++) {
            const int fp = ks ? fpos1 : fpos0;
            short8 a[4], b[4];
#pragma unroll
            for (int i = 0; i < 4; i++)
                a[i] = *(const short8*)(Ac + (wm*64 + i*16 + l16)*64 + fp);
#pragma unroll
            for (int i = 0; i < 4; i++)
                b[i] = *(const short8*)(Bc + (wn*64 + i*16 + l16)*64 + fp);
#pragma unroll
            for (int i = 0; i < 4; i++)
#pragma unroll
                for (int j = 0; j < 4; j++)
                    acc[i][j] = __builtin_amdgcn_mfma_f32_16x16x32_bf16(a[i], b[j], acc[i][j], 0, 0, 0);
        }
    }

    // ---- cross-group K-reduce through LDS (64 KB = 16384 floats, exact fit) ----
    __syncthreads();                      // all waves done reading S
    float* X = (float*)&S[0][0];
    if (g == 1) {
#pragma unroll
        for (int i = 0; i < 4; i++)
#pragma unroll
            for (int j = 0; j < 4; j++)
#pragma unroll
                for (int r = 0; r < 4; r++)
                    X[((i*4 + j)*4 + r) * 256 + t] = acc[i][j][r];  // lane-stride: conflict-free
    }
    __syncthreads();
    if (g == 0) {
#pragma unroll
        for (int i = 0; i < 4; i++) {
#pragma unroll
            for (int j = 0; j < 4; j++) {
                const int col = bn0 + wn*64 + j*16 + l16;
                const float bvv = bias[col];
#pragma unroll
                for (int r = 0; r < 4; r++) {
                    const float v = acc[i][j][r] + X[((i*4 + j)*4 + r) * 256 + t] + bvv;
                    const int row = bm0 + wm*64 + i*16 + quad*4 + r;
                    out[(size_t)row * EMBED + col] = v;
                }
            }
        }
    }
}

// ---------------- flash attention: ONE 128-q tile per block, largest-qb-first ----------------
// Un-paired version of the verified 128q kernel: grid 1024 = 64 bh x 16 q-tiles
// (was 512 blocks x 2 passes). Inner loop byte-identical. LDS 48 KB -> 3 blocks/CU
// resident (was grid-capped at 2); qb = 15-(s>>3) puts the 32-kt blocks first so
// short blocks fill the scheduling tail. XCD-grouped as before (lid&7).
__global__ __launch_bounds__(256)
void attn_kernel(const u16* __restrict__ Q, const u16* __restrict__ K,
                 const u16* __restrict__ Vt, u16* __restrict__ O)
{
    __shared__ u16 Ks[2][64*64];     // 2 x 8 KB
    __shared__ u16 Vs[2][64*64];     // 2 x 8 KB   Vs[d][ki]
    __shared__ u16 Ps[4*32*64];      // 16 KB, per-wave 32 rows x 64 ki

    const int tid  = threadIdx.x, lane = tid & 63, w = tid >> 6;
    const int quad = lane >> 4, l16 = lane & 15;

    const int lid  = blockIdx.x;            // 0..1023
    const int xcd  = lid & 7;
    const int s    = lid >> 3;              // 0..127
    const int qb   = 15 - (s >> 3);         // 15..0, largest first
    const int bh   = xcd * 8 + (s & 7);     // 0..63
    const int h    = bh & (HEADS - 1);
    const int b    = bh >> 4;

    const u16* Qh = Q  + (size_t)bh * CTX * HD;
    const u16* Kh = K  + (size_t)bh * CTX * HD;
    const u16* Vh = Vt + (size_t)bh * HD * CTX;

    const int srow = tid >> 3;
    const int joff = ((tid & 7) ^ (srow & 7)) * 8;
    const int wbyte = w * 1024;
    char* PwB = (char*)(Ps + w * 32 * 64);
    const int sw = l16 & 7;                 // swizzle key (row&7 for all our rows)

    short8 ones;                            // bf16 1.0 x8
#pragma unroll
    for (int i = 0; i < 8; i++) ones[i] = (short)0x3F80;

    auto stage = [&](int kt, int buf) {
        char* kb = (char*)(&Ks[buf][0]) + wbyte;
        char* vb = (char*)(&Vs[buf][0]) + wbyte;
        async16(Kh + (size_t)(kt*64 + srow     )*HD + joff, kb);
        async16(Kh + (size_t)(kt*64 + srow + 32)*HD + joff, kb + 4096);
        async16(Vh + (size_t)(srow     )*CTX + kt*64 + joff, vb);
        async16(Vh + (size_t)(srow + 32)*CTX + kt*64 + joff, vb + 4096);
    };

    int par = 0;
    stage(0, 0);

    const int qb0 = qb * 128;
    const int KT  = 2*qb + 2;

    // Q fragments (B-operand: n=q=l16, k=d): qf[subtile][kstep]
    short8 qf[2][2];
#pragma unroll
    for (int st = 0; st < 2; st++)
#pragma unroll
        for (int ks = 0; ks < 2; ks++)
            qf[st][ks] = *(const short8*)(Qh + (size_t)(qb0 + w*32 + st*16 + l16)*HD
                                          + ks*32 + quad*8);

    floatx4 lacc[2] = {};        // row-sum accumulators (ones-MFMA)
    floatx4 o_acc[2][4] = {};

    for (int kt = 0; kt < KT; kt++) {
        __syncthreads();   // drains stage(kt), in flight since previous compute

        if (kt + 1 < KT) stage(kt + 1, par ^ 1);

        const char* KcB = (const char*)(&Ks[par][0]);
        const char* VcB = (const char*)(&Vs[par][0]);

        // S^T = K Q^T : m=ki (row=quad*4+r), n=q (col=l16)
        floatx4 sx[2][4] = {};
#pragma unroll
        for (int ks = 0; ks < 2; ks++) {
#pragma unroll
            for (int ni = 0; ni < 4; ni++) {
                short8 kf = *(const short8*)(KcB + (ni*16 + l16)*128
                                             + (((4*ks + quad) ^ sw) * 16));
                sx[0][ni] = __builtin_amdgcn_mfma_f32_16x16x32_bf16(kf, qf[0][ks], sx[0][ni], 0, 0, 0);
                sx[1][ni] = __builtin_amdgcn_mfma_f32_16x16x32_bf16(kf, qf[1][ks], sx[1][ni], 0, 0, 0);
            }
        }

        // P = exp2(S'), mask on last two tiles, packed b64 stores to swizzled P
        const bool mt = (kt >= 2*qb);
        const int key0 = kt * 64;
#pragma unroll
        for (int st = 0; st < 2; st++) {
            const int qrow = qb0 + w*32 + st*16 + l16;
#pragma unroll
            for (int ni = 0; ni < 4; ni++) {
                float p[4];
#pragma unroll
                for (int r = 0; r < 4; r++) {
                    float v = sx[st][ni][r];
                    if (mt) {
                        const int key = key0 + ni*16 + quad*4 + r;
                        if (key > qrow) v = -INFINITY;
                    }
                    p[r] = __builtin_amdgcn_exp2f(v);
                }
                uint2 pk;
                pk.x = (__float_as_uint(p[0]) >> 16) | (__float_as_uint(p[1]) & 0xFFFF0000u);
                pk.y = (__float_as_uint(p[2]) >> 16) | (__float_as_uint(p[3]) & 0xFFFF0000u);
                *(uint2*)(PwB + (st*16 + l16)*128
                          + (((2*ni + (quad >> 1)) ^ sw) * 16) + (quad & 1) * 8) = pk;
            }
        }

        // O += P V : A=P (m=q), B=Vt rows (n=d, k=ki); lacc += P * ones
#pragma unroll
        for (int ks = 0; ks < 2; ks++) {
            const int pco = ((4*ks + quad) ^ sw) * 16;
            short8 pf0 = *(const short8*)(PwB + (l16     )*128 + pco);
            short8 pf1 = *(const short8*)(PwB + (16 + l16)*128 + pco);
            lacc[0] = __builtin_amdgcn_mfma_f32_16x16x32_bf16(pf0, ones, lacc[0], 0, 0, 0);
            lacc[1] = __builtin_amdgcn_mfma_f32_16x16x32_bf16(pf1, ones, lacc[1], 0, 0, 0);
#pragma unroll
            for (int ni = 0; ni < 4; ni++) {
                short8 vf = *(const short8*)(VcB + (ni*16 + l16)*128 + pco);
                o_acc[0][ni] = __builtin_amdgcn_mfma_f32_16x16x32_bf16(pf0, vf, o_acc[0][ni], 0, 0, 0);
                o_acc[1][ni] = __builtin_amdgcn_mfma_f32_16x16x32_bf16(pf1, vf, o_acc[1][ni], 0, 0, 0);
            }
        }

        par ^= 1;
    }

    // lacc[st][r] = row-sum for q = qb0 + w*32 + st*16 + quad*4 + r (all cols equal)
    float linv[2][4];
#pragma unroll
    for (int st = 0; st < 2; st++)
#pragma unroll
        for (int r = 0; r < 4; r++)
            linv[st][r] = 1.0f / lacc[st][r];

    u16* Ob = O + ((size_t)b * CTX) * EMBED + (size_t)h * HD;
#pragma unroll
    for (int st = 0; st < 2; st++)
#pragma unroll
        for (int ni = 0; ni < 4; ni++)
#pragma unroll
            for (int r = 0; r < 4; r++) {
                const int qrow = qb0 + w*32 + st*16 + quad*4 + r;
                Ob[(size_t)qrow * EMBED + ni*16 + l16] = f2bf(o_acc[st][ni][r] * linv[st][r]);
            }
}

// ---------------- launcher ----------------
extern "C" void kernel_launch(void* const* d_in, const int* in_sizes, int n_in,
                              void* d_out, int out_size, void* d_ws, size_t ws_size,
                              hipStream_t stream) {
    const float* x  = (const float*)d_in[0];
    const float* Wq = (const float*)d_in[1];
    const float* bq = (const float*)d_in[2];
    const float* Wk = (const float*)d_in[3];
    const float* bk = (const float*)d_in[4];
    const float* Wv = (const float*)d_in[5];
    const float* bv = (const float*)d_in[6];
    const float* Wp = (const float*)d_in[7];
    const float* bp = (const float*)d_in[8];

    char* ws = (char*)d_ws;
    const size_t XSZ = (size_t)M_TOT * EMBED * 2;   // 16 MB
    const size_t WSZ = (size_t)EMBED * EMBED * 2;   // 2 MB
    u16* xb  = (u16*)ws;                 ws += XSZ;
    u16* wqb = (u16*)ws;                 ws += WSZ;
    u16* wkb = (u16*)ws;                 ws += WSZ;
    u16* wvb = (u16*)ws;                 ws += WSZ;
    u16* wpb = (u16*)ws;                 ws += WSZ;
    u16* qg  = (u16*)ws;                 ws += XSZ;
    u16* kg  = (u16*)ws;                 ws += XSZ;
    u16* vtg = (u16*)ws;                 ws += XSZ;
    u16* og  = xb;   // x-bf16 dead after QKV GEMM; attn output reuses it

    cvt_all<<<12288, 256, 0, stream>>>(x, Wq, Wk, Wv, Wp, xb, wqb, wkb, wvb, wpb);

    const float qscale = 0.125f * 1.44269504f;  // 1/sqrt(64) * log2(e)
    gemm_qkv<<<dim3(M_TOT/128, 24), 256, 0, stream>>>(xb, wqb, wkb, wvb, bq, bk, bv,
                                                      qg, kg, vtg, qscale);

    attn_kernel<<<dim3(1024), 256, 0, stream>>>(qg, kg, vtg, og);

    gemm_proj<<<dim3(M_TOT/128, EMBED/128), 512, 0, stream>>>(og, wpb, bp, (float*)d_out);
}